// Round 3
// baseline (279.468 us; speedup 1.0000x reference)
//
#include <hip/hip_runtime.h>
#include <cstdint>
#include <cstddef>
#include <type_traits>

typedef float  f32x4    __attribute__((ext_vector_type(4)));
typedef float  f32x16   __attribute__((ext_vector_type(16)));
typedef __bf16 bf16x8   __attribute__((ext_vector_type(8)));
typedef short  short4_t __attribute__((ext_vector_type(4)));
typedef short  short8_t __attribute__((ext_vector_type(8)));
typedef unsigned int uint4_t __attribute__((ext_vector_type(4)));

// hw f32->bf16 (v_cvt_pk_bf16_f32 on gfx950), RNE
__device__ __forceinline__ short f2bf(float f) {
  return __builtin_bit_cast(short, (__bf16)f);
}

__device__ __forceinline__ unsigned pk2bf(float a, float b) {
  unsigned lo = (unsigned short)__builtin_bit_cast(unsigned short, f2bf(a));
  unsigned hi = (unsigned short)__builtin_bit_cast(unsigned short, f2bf(b));
  return lo | (hi << 16);
}

__device__ __forceinline__ void gl_lds16(const void* g, void* l) {
  __builtin_amdgcn_global_load_lds((const __attribute__((address_space(1))) void*)g,
                                   (__attribute__((address_space(3))) void*)l, 16, 0, 0);
}

// ---------------- elementwise fp32 -> bf16 ----------------
__global__ void convert_bf16(const float* __restrict__ X, short* __restrict__ Xb) {
  int i = (blockIdx.x * 256 + threadIdx.x) * 4;
  f32x4 v = *(const f32x4*)&X[i];
  short4_t o;
#pragma unroll
  for (int j = 0; j < 4; j++) o[j] = f2bf(v[j]);
  *(short4_t*)&Xb[i] = o;
}

// ---------------- transpose-convert W[K][N] fp32 -> WT[N][K] bf16 ----------------
__global__ void transpose_bf16(const float* __restrict__ W, short* __restrict__ WT,
                               int K, int N) {
  __shared__ float tile[32][33];
  int tx = threadIdx.x & 31, ty = threadIdx.x >> 5;    // ty 0..7
  int n0 = blockIdx.x * 32, k0 = blockIdx.y * 32;
#pragma unroll
  for (int i = 0; i < 32; i += 8)
    tile[ty + i][tx] = W[(size_t)(k0 + ty + i) * N + n0 + tx];
  __syncthreads();
#pragma unroll
  for (int i = 0; i < 32; i += 8)
    WT[(size_t)(n0 + ty + i) * K + k0 + tx] = f2bf(tile[tx][ty + i]);
}

// ---------------- m97-style 128^2 bf16 GEMM (kept for proj), Bt is [N][K] ----------------
__global__ __launch_bounds__(256, 2) void gemm_bt(
    const short* __restrict__ A, const short* __restrict__ Bt,
    float* __restrict__ outf, int M, int N, int K) {
  __shared__ alignas(16) short As[128 * 32];
  __shared__ alignas(16) short Bs[128 * 32];
  const int tid = threadIdx.x;
  const int lane = tid & 63;
  const int g = lane & 15, q = lane >> 4;
  const int wave = tid >> 6;
  const int m0 = blockIdx.y * 128, n0 = blockIdx.x * 128;
  const int wm = (wave >> 1) * 64, wn = (wave & 1) * 64;

  const int srow = tid >> 2;            // 0..63
  const int scol = (tid & 3) * 8;       // element col within BK
  const short* ap0 = A  + (size_t)(m0 + srow) * K + scol;
  const short* ap1 = A  + (size_t)(m0 + 64 + srow) * K + scol;
  const short* bp0 = Bt + (size_t)(n0 + srow) * K + scol;
  const short* bp1 = Bt + (size_t)(n0 + 64 + srow) * K + scol;
  short* la0 = &As[tid * 8];
  short* la1 = &As[(tid + 256) * 8];
  short* lb0 = &Bs[tid * 8];
  short* lb1 = &Bs[(tid + 256) * 8];

  f32x4 acc[4][4] = {};

  for (int k0 = 0; k0 < K; k0 += 32) {
    __syncthreads();
    gl_lds16(ap0 + k0, la0);
    gl_lds16(ap1 + k0, la1);
    gl_lds16(bp0 + k0, lb0);
    gl_lds16(bp1 + k0, lb1);
    __syncthreads();
    bf16x8 af[4], bfr[4];
#pragma unroll
    for (int mt = 0; mt < 4; mt++)
      af[mt] = *(const bf16x8*)&As[(wm + mt * 16 + g) * 32 + q * 8];
#pragma unroll
    for (int nt = 0; nt < 4; nt++)
      bfr[nt] = *(const bf16x8*)&Bs[(wn + nt * 16 + g) * 32 + q * 8];
#pragma unroll
    for (int mt = 0; mt < 4; mt++)
#pragma unroll
      for (int nt = 0; nt < 4; nt++)
        acc[mt][nt] = __builtin_amdgcn_mfma_f32_16x16x32_bf16(af[mt], bfr[nt],
                                                              acc[mt][nt], 0, 0, 0);
  }

#pragma unroll
  for (int mt = 0; mt < 4; mt++)
#pragma unroll
    for (int nt = 0; nt < 4; nt++) {
      int n = n0 + wn + nt * 16 + g;
      int mbase = m0 + wm + mt * 16 + q * 4;
#pragma unroll
      for (int r = 0; r < 4; r++)
        outf[(size_t)(mbase + r) * N + n] = acc[mt][nt][r];
    }
}

// ---------------- 256^2 8-phase QKV GEMM (T1+T2+T3+T4+T5) ----------------
// A [M][K] bf16, Bt [N][K] bf16. Scatters bf16 into Q/K [B,H,T,D], V^T [B,H,D,T].
// 512 threads = 8 waves (2 Mx4 N); per-wave output 128x64; acc 8x4 f32x4.
// BK=64. LDS 128 KiB: 2 bufs x (A 32KB + B 32KB), each tile = 2048 16B "units",
// unit u = ((sub16*2 + kk)*4 + q)*16 + g  (sub16 = row/16, kk = k-half of 64,
// q = k-quarter within 32, g = row%16). Fragment read (sub16, kk) = units
// [base, base+64) -> 64 lanes x contiguous 16B = bank-conflict-free; staged by
// global_load_lds with per-lane pre-permuted global source (linear LDS dest).
// Halves: h0 = rows 0..127 (units 0..1023), h1 = rows 128..255.
// 8 phases / iteration, 2 K-tiles (T0->buf0 ph1-4, T1->buf1 ph5-8), quadrant
// order (mh,nh): (0,0)(0,1)(1,1)(1,0). Stage schedule (derived; every half
// staged >=3 phases before first ds_read, overwrite >=1 barrier after last read):
//   ph1: T1.b0   ph2: T1.a1   ph3: T2.a0   ph4: T2.b1
//   ph5: T2.b0   ph6: T2.a1   ph7: T3.a0   ph8: T3.b1
// vmcnt(6) (= 3 half-tiles, 2 loads each) every phase, never 0 in the loop.
__global__ __launch_bounds__(512, 2) void gemm256_qkv(
    const short* __restrict__ A, const short* __restrict__ Bt,
    short* __restrict__ Qo, short* __restrict__ Ko, short* __restrict__ Vo,
    int M, int N, int K) {
  __shared__ alignas(16) short As2[2][16384];
  __shared__ alignas(16) short Bs2[2][16384];
  const int tid = threadIdx.x;
  const int lane = tid & 63;
  const int g = lane & 15, q = lane >> 4;
  const int wave = tid >> 6;
  const int wr = wave >> 2, wc = wave & 3;

  // XCD-aware bijective swizzle (nwg = 384, %8 == 0)
  const int cpx = (gridDim.x * gridDim.y) >> 3;
  const int lin = blockIdx.x + gridDim.x * blockIdx.y;
  const int swz = (lin & 7) * cpx + (lin >> 3);
  const int bx = swz % gridDim.x, by = swz / gridDim.x;
  const int m0 = by * 256, n0 = bx * 256;

  const int nkt = K >> 6;   // 64-wide K-tiles (16 for K=1024)

  // stage source decomposition: unit u = c*512 + tid (c = chunk 0/1)
  const int srow  = (tid >> 7) * 16 + (tid & 15);
  const int skoff = ((tid >> 6) & 1) * 32 + ((tid >> 4) & 3) * 8;

  auto stA = [&](int buf, int h, int t) {
    int tw = t & (nkt - 1);                      // wrap: tail stages harmless
    const short* src = A + (size_t)(m0 + h * 128 + srow) * K + tw * 64 + skoff;
    short* dst = &As2[buf][(h * 1024 + tid) * 8];
    gl_lds16(src, dst);
    gl_lds16(src + (size_t)64 * K, dst + 4096);  // chunk 1: +64 rows, +512 units
  };
  auto stB = [&](int buf, int h, int t) {
    int tw = t & (nkt - 1);
    const short* src = Bt + (size_t)(n0 + h * 128 + srow) * K + tw * 64 + skoff;
    short* dst = &Bs2[buf][(h * 1024 + tid) * 8];
    gl_lds16(src, dst);
    gl_lds16(src + (size_t)64 * K, dst + 4096);
  };

  bf16x8 afr[4][2], bfr[4][2];
  f32x4 acc[8][4] = {};

  auto rdA = [&](int buf, int mh) {
#pragma unroll
    for (int mt = 0; mt < 4; mt++)
#pragma unroll
      for (int kk = 0; kk < 2; kk++)
        afr[mt][kk] = *(const bf16x8*)
            &As2[buf][(((wr * 8 + mh * 4 + mt) * 2 + kk) * 64 + lane) * 8];
  };
  auto rdB = [&](int buf, int nh) {
#pragma unroll
    for (int j = 0; j < 2; j++)
#pragma unroll
      for (int kk = 0; kk < 2; kk++)
        bfr[nh * 2 + j][kk] = *(const bf16x8*)
            &Bs2[buf][(((wc * 4 + nh * 2 + j) * 2 + kk) * 64 + lane) * 8];
  };
  auto quad = [&](int mh, int nh) {
#pragma unroll
    for (int kk = 0; kk < 2; kk++)
#pragma unroll
      for (int mt = 0; mt < 4; mt++)
#pragma unroll
        for (int j = 0; j < 2; j++)
          acc[mh * 4 + mt][nh * 2 + j] = __builtin_amdgcn_mfma_f32_16x16x32_bf16(
              afr[mt][kk], bfr[nh * 2 + j][kk], acc[mh * 4 + mt][nh * 2 + j], 0, 0, 0);
  };
  auto sync1 = [&]() {
    asm volatile("s_waitcnt vmcnt(6)" ::: "memory");
    __builtin_amdgcn_s_barrier();
    asm volatile("s_waitcnt lgkmcnt(0)" ::: "memory");
    __builtin_amdgcn_sched_barrier(0);
    __builtin_amdgcn_s_setprio(1);
  };
  auto sync2 = [&]() {
    __builtin_amdgcn_s_setprio(0);
    __builtin_amdgcn_s_barrier();
  };

  // prologue: mimic steady-state history (prev ph3..ph8)
  stA(0, 0, 0);   // T0.a0
  stB(0, 1, 0);   // T0.b1
  stB(0, 0, 0);   // T0.b0
  stA(0, 1, 0);   // T0.a1
  stA(1, 0, 1);   // T1.a0
  stB(1, 1, 1);   // T1.b1
  asm volatile("s_waitcnt vmcnt(6)" ::: "memory");
  __builtin_amdgcn_s_barrier();

  const int niter = nkt >> 1;
  for (int i = 0; i < niter; i++) {
    const int t0 = 2 * i;
    // ph1
    rdA(0, 0); rdB(0, 0);
    stB(1, 0, t0 + 1);
    sync1(); quad(0, 0); sync2();
    // ph2
    rdB(0, 1);
    stA(1, 1, t0 + 1);
    sync1(); quad(0, 1); sync2();
    // ph3
    rdA(0, 1);
    stA(0, 0, t0 + 2);
    sync1(); quad(1, 1); sync2();
    // ph4
    stB(0, 1, t0 + 2);
    sync1(); quad(1, 0); sync2();
    // ph5
    rdA(1, 0); rdB(1, 0);
    stB(0, 0, t0 + 2);
    sync1(); quad(0, 0); sync2();
    // ph6
    rdB(1, 1);
    stA(0, 1, t0 + 2);
    sync1(); quad(0, 1); sync2();
    // ph7
    rdA(1, 1);
    stA(1, 0, t0 + 3);
    sync1(); quad(1, 1); sync2();
    // ph8
    stB(1, 1, t0 + 3);
    sync1(); quad(1, 0); sync2();
  }
  asm volatile("s_waitcnt vmcnt(0)" ::: "memory");  // retire safety

  // epilogue: scatter bf16 into Q/K [B,H,T,D] and V^T [B,H,D,T]
#pragma unroll
  for (int an = 0; an < 4; an++) {
    int n = n0 + wc * 64 + an * 16 + g;
    int which = n >> 10;            // 0=q 1=k 2=v (uniform per block)
    int cc = n & 1023;
    int hh = cc >> 6, d = cc & 63;
#pragma unroll
    for (int am = 0; am < 8; am++) {
      int mbase = m0 + wr * 128 + am * 16 + q * 4;
      int b = mbase >> 11, t = mbase & 2047;   // 4 rows never cross b
      if (which == 2) {
        short4_t pv;
#pragma unroll
        for (int r = 0; r < 4; r++) pv[r] = f2bf(acc[am][an][r]);
        *(short4_t*)&Vo[((size_t)((b << 4) + hh) * 64 + d) * 2048 + t] = pv;
      } else {
        short* dst = (which == 0) ? Qo : Ko;
#pragma unroll
        for (int r = 0; r < 4; r++)
          dst[((size_t)((b << 4) + hh) * 2048 + (t + r)) * 64 + d] =
              f2bf(acc[am][an][r]);
      }
    }
  }
}

// ---------------- causal flash attention, 32x32 MFMA ----------------
// (unchanged from R2 — harness-verified)
__global__ __launch_bounds__(256, 2) void attn_fwd(
    const short* __restrict__ Qg, const short* __restrict__ Kg,
    const short* __restrict__ Vt, short* __restrict__ Og) {
  __shared__ alignas(16) short Ks[2][8192];   // 2 x 16 KB
  __shared__ alignas(16) short Vs[2][8192];   // 2 x 16 KB
  const int tid = threadIdx.x, lane = tid & 63, wave = tid >> 6;
  const int c = lane & 31;        // q-row within the wave's 32-row subtile
  const int qh = lane >> 5;       // 0/1: k-half of fragments
  const int bh = blockIdx.x;      // bh fastest => q-blocks of a bh co-XCD
  const int b = bh >> 4, h = bh & 15;
  const size_t base = (size_t)bh * (2048 * 64);
  const float cs = 0.18033688011f;     // (1/sqrt(64)) * log2(e)
  const int q_rel = wave * 32 + c;
  const int laneoff = (qh * 32 + c) * 8;   // short offset of lane's 16B slot

  // per-thread stage sources (tile-invariant parts precomputed)
  const short* kp[4];
  const short* vp[4];
#pragma unroll
  for (int i = 0; i < 4; i++) {
    int u = i * 256 + tid;
    int uc = u & 31, uq = (u >> 5) & 1;
    kp[i] = Kg + base + (size_t)((u >> 8) * 32 + uc) * 64 + ((u >> 6) & 3) * 16 + uq * 8;
    vp[i] = Vt + base + (size_t)(((u >> 6) & 1) * 32 + uc) * 2048 + (u >> 7) * 16 + uq * 8;
  }

  auto stage = [&](int buf, int kt) {
    short* kd = &Ks[buf][tid * 8];
    short* vd = &Vs[buf][tid * 8];
#pragma unroll
    for (int i = 0; i < 4; i++) {
      gl_lds16(kp[i] + (size_t)kt * (128 * 64), kd + i * 2048);
      gl_lds16(vp[i] + (size_t)kt * 128, vd + i * 2048);
    }
  };

  int cur = 0;

  for (int half = 0; half < 2; half++) {
    const int qt = (half == 0) ? (int)blockIdx.y : 15 - (int)blockIdx.y;
    const int qrow = qt * 128 + wave * 32 + c;

    // Q fragments (pre-scaled), one q-row per lane
    bf16x8 bq[4];
#pragma unroll
    for (int ks = 0; ks < 4; ks++) {
      bf16x8 v = *(const bf16x8*)&Qg[base + (size_t)qrow * 64 + ks * 16 + qh * 8];
#pragma unroll
      for (int j = 0; j < 8; j++) v[j] = (__bf16)((float)v[j] * cs);
      bq[ks] = v;
    }

    f32x16 ot[2] = {};                  // O^T acc: d-tiles {0..31},{32..63}
    float m_run = -1e30f, l_run = 0.0f;

    auto step = [&](auto diagc, const short* ksb, const short* vsb) {
      constexpr bool DIAG = decltype(diagc)::value;

      // ---- S^T = K * Q^T (K frags straight from LDS, conflict-free) ----
      f32x16 st[4] = {};
      __builtin_amdgcn_s_setprio(1);
#pragma unroll
      for (int mt = 0; mt < 4; mt++)
#pragma unroll
        for (int ks = 0; ks < 4; ks++) {
          bf16x8 ak = *(const bf16x8*)&ksb[(mt * 4 + ks) * 512 + laneoff];
          st[mt] = __builtin_amdgcn_mfma_f32_32x32x16_bf16(ak, bq[ks],
                                                           st[mt], 0, 0, 0);
        }
      __builtin_amdgcn_s_setprio(0);

      // ---- softmax (in-register; one shfl pair with lane^32) ----
      float tm[4];
#pragma unroll
      for (int mt = 0; mt < 4; mt++) {
        float t = -1e30f;
#pragma unroll
        for (int r = 0; r < 16; r++) {
          if (DIAG) {
            int krel = mt * 32 + (r & 3) + 8 * (r >> 2) + 4 * qh;
            if (krel > q_rel) st[mt][r] = -1e30f;
          }
          t = fmaxf(t, st[mt][r]);
        }
        tm[mt] = t;
      }
      float tmax = fmaxf(fmaxf(tm[0], tm[1]), fmaxf(tm[2], tm[3]));
      tmax = fmaxf(tmax, __shfl_xor(tmax, 32));
      // defer-max (T13): skip O-rescale while max growth bounded (P <= 2^8)
      if (!__all(tmax - m_run <= 8.0f)) {
        const float mnew = fmaxf(m_run, tmax);
        const float alpha = __builtin_amdgcn_exp2f(m_run - mnew);
        l_run *= alpha;
#pragma unroll
        for (int mt = 0; mt < 2; mt++)
#pragma unroll
          for (int r = 0; r < 16; r++) ot[mt][r] *= alpha;
        m_run = mnew;
      }
      float ps[4];
#pragma unroll
      for (int mt = 0; mt < 4; mt++) {
        float s = 0.0f;
#pragma unroll
        for (int r = 0; r < 16; r++) {
          float p = __builtin_amdgcn_exp2f(st[mt][r] - m_run);
          s += p;
          st[mt][r] = p;
        }
        ps[mt] = s;
      }
      float psum = (ps[0] + ps[1]) + (ps[2] + ps[3]);
      psum += __shfl_xor(psum, 32);
      l_run += psum;

      // ---- O^T += V^T * P^T (P^T built in-register via permlane32_swap) ----
      __builtin_amdgcn_s_setprio(1);
#pragma unroll
      for (int kb = 0; kb < 8; kb++) {
        const int mt = kb >> 1, rb = (kb & 1) * 8;
        unsigned x0 = pk2bf(st[mt][rb + 0], st[mt][rb + 1]);
        unsigned x1 = pk2bf(st[mt][rb + 2], st[mt][rb + 3]);
        unsigned y0 = pk2bf(st[mt][rb + 4], st[mt][rb + 5]);
        unsigned y1 = pk2bf(st[mt][rb + 6], st[mt][rb + 7]);
        asm("v_permlane32_swap_b32 %0, %1" : "+v"(x0), "+v"(y0));
        asm("v_permlane32_swap_b32 %0, %1" : "+v"(x1), "+v"(y1));
        uint4_t pw;
        pw[0] = x0; pw[1] = x1; pw[2] = y0; pw[3] = y1;
        bf16x8 pb = __builtin_bit_cast(bf16x8, pw);
#pragma unroll
        for (int mtv = 0; mtv < 2; mtv++) {
          bf16x8 av = *(const bf16x8*)&vsb[(kb * 2 + mtv) * 512 + laneoff];
          ot[mtv] = __builtin_amdgcn_mfma_f32_32x32x16_bf16(av, pb,
                                                            ot[mtv], 0, 0, 0);
        }
      }
      __builtin_amdgcn_s_setprio(0);
    };

    __syncthreads();                    // buffers free (prior half done)
    stage(cur, 0);
    for (int kt = 0; kt <= qt; kt++) {
      __syncthreads();                  // vmcnt(0) drain => buf[cur] ready
      if (kt < qt) stage(cur ^ 1, kt + 1);   // prefetch overlaps compute
      if (kt == qt)
        step(std::integral_constant<bool, true>{}, Ks[cur], Vs[cur]);
      else
        step(std::integral_constant<bool, false>{}, Ks[cur], Vs[cur]);
      cur ^= 1;
    }

    // ---- epilogue: O[b, qrow, h*64+d] = O^T / l ----
    const float inv = 1.0f / l_run;
    const size_t obase = ((size_t)b * 2048 + qrow) * 1024 + h * 64 + qh * 4;
#pragma unroll
    for (int mt = 0; mt < 2; mt++)
#pragma unroll
      for (int rr = 0; rr < 4; rr++) {
        short4_t ov;
#pragma unroll
        for (int i = 0; i < 4; i++) ov[i] = f2bf(ot[mt][rr * 4 + i] * inv);
        *(short4_t*)&Og[obase + mt * 32 + rr * 8] = ov;
      }
  }
}

// ---------------- launch ----------------
extern "C" void kernel_launch(void* const* d_in, const int* in_sizes, int n_in,
                              void* d_out, int out_size, void* d_ws, size_t ws_size,
                              hipStream_t stream) {
  const float* x      = (const float*)d_in[0];   // [4,2048,1024]
  const float* w_qkv  = (const float*)d_in[1];   // [1024,3072]
  const float* w_proj = (const float*)d_in[2];   // [1024,1024]
  float* out = (float*)d_out;                    // [4,2048,1024]

  char* ws = (char*)d_ws;
  short* xb     = (short*)(ws);                    // 16 MB bf16 x; reused as O
  short* wqkvT  = (short*)(ws + 16777216);         // 6 MB
  short* wprojT = (short*)(ws + 23068672);         // 2 MB
  short* Qb     = (short*)(ws + 25165824);         // 16 MB  [B,H,T,D]
  short* Kb     = (short*)(ws + 41943040);         // 16 MB  [B,H,T,D]
  short* Vtb    = (short*)(ws + 58720256);         // 16 MB  [B,H,D,T]

  convert_bf16<<<8192, 256, 0, stream>>>(x, xb);
  {
    dim3 gq(96, 32); transpose_bf16<<<gq, 256, 0, stream>>>(w_qkv, wqkvT, 1024, 3072);
    dim3 gp(32, 32); transpose_bf16<<<gp, 256, 0, stream>>>(w_proj, wprojT, 1024, 1024);
  }
  {
    dim3 g(12, 32);  // N/256, M/256 = 384 blocks (%8==0 for XCD swizzle)
    gemm256_qkv<<<g, 512, 0, stream>>>(xb, wqkvT, Qb, Kb, Vtb, 8192, 3072, 1024);
  }
  {
    // grid: x = b*h (same bh -> same XCD under linear%8 round-robin),
    //       y = paired q-tiles (qt, 15-qt) -> uniform 17 k-iterations
    dim3 g(64, 8);
    attn_fwd<<<g, 256, 0, stream>>>(Qb, Kb, Vtb, xb /* O, reusing xb */);
  }
  {
    dim3 g(8, 64);
    gemm_bt<<<g, 256, 0, stream>>>(xb, wprojT, out, 8192, 1024, 1024);
  }
}